// Round 9
// baseline (1673.611 us; speedup 1.0000x reference)
//
#include <hip/hip_runtime.h>
#include <hip/hip_bf16.h>

#define D 256
#define TE 128         // messages per tile
#define NB 128         // output cols per block (colhalf)
#define BK 64          // K-chunk
#define NCHUNK 12      // 4 groups x [E | E*H | H]
#define LEAKY 0.01f
#define EPS 1e-5f

typedef float f32x4 __attribute__((ext_vector_type(4)));
typedef short s16x8 __attribute__((ext_vector_type(8)));

__device__ __forceinline__ unsigned short f2bf(float f){
  union { float f; unsigned int u; } v; v.f = f;
  unsigned int u = v.u;
  return (unsigned short)((u + 0x7fffu + ((u >> 16) & 1u)) >> 16);
}
__device__ __forceinline__ unsigned int pack2(float a, float b){
  return (unsigned int)f2bf(a) | ((unsigned int)f2bf(b) << 16);
}
__device__ __forceinline__ s16x8 pack8(float4 a, float4 b){
  union { s16x8 v; unsigned int u[4]; } r;
  r.u[0] = pack2(a.x, a.y); r.u[1] = pack2(a.z, a.w);
  r.u[2] = pack2(b.x, b.y); r.u[3] = pack2(b.z, b.w);
  return r.v;
}

// Plain-layout bf16 images of folded weights, per (dir, colhalf, chunk).
// K reorder: group g in 0..3, parts [E_g | (E*H)_g | H_g], chunk c = g*3+part.
// Tile t = (dir*2+h)*12 + c (16 KB): byte off = j*128 + k*2 (j=local col, k=local K).
__global__ void prep_w(const float* __restrict__ Wf, const float* __restrict__ Wb,
                       unsigned short* __restrict__ Wimg)
{
  int i = blockIdx.x * 256 + threadIdx.x;       // 2*2*12*128*64 = 393216
  int inner = i & 8191;                         // j*64 + k
  int t = i >> 13;                              // (dir*2+h)*12 + c
  int c = t % 12;
  int q = t / 12;
  int dir = q >> 1, h = q & 1;
  int g = c / 3, part = c - g * 3;
  int j = inner >> 6, k = inner & 63;
  int x = g * 64 + k;                           // original feature index
  const float* row = (dir ? Wb : Wf) + (long)(h * NB + j) * (4 * D);
  // raw = [Hh | E | Hh+E | Hh*E]:
  float v;
  if (part == 0)      v = row[256 + x] + row[512 + x];   // E coeff
  else if (part == 1) v = row[768 + x];                  // Hh*E coeff
  else                v = row[x] + row[512 + x];         // Hh coeff
  *(unsigned short*)((char*)Wimg + (size_t)t * 16384 + j * 128 + k * 2) = f2bf(v);
}

// Per-dir dst histogram: cnt[0..n) = fwd (dst=tail), cnt[n..2n) = back (dst=head)
__global__ void count2(const int* __restrict__ ht, int* __restrict__ cnt,
                       int n_edges, int n_nodes)
{
  int e = blockIdx.x * 256 + threadIdx.x;
  if (e < n_edges){
    atomicAdd(&cnt[ht[2*e+1]], 1);
    atomicAdd(&cnt[n_nodes + ht[2*e]], 1);
  }
}

__global__ void scan_sums(const int* __restrict__ cnt, int* __restrict__ bsum, int N2)
{
  int t = threadIdx.x, b = blockIdx.x;
  int i = b * 1024 + t;
  int v = (i < N2) ? cnt[i] : 0;
  #pragma unroll
  for (int o = 32; o > 0; o >>= 1) v += __shfl_down(v, o);
  __shared__ int red[16];
  int lane = t & 63, wv = t >> 6;
  if (lane == 0) red[wv] = v;
  __syncthreads();
  if (t == 0){ int s = 0; for (int k = 0; k < 16; ++k) s += red[k]; bsum[b] = s; }
}

__global__ void scan_bases(const int* __restrict__ bsum, int* __restrict__ bases, int nb)
{
  if (threadIdx.x == 0 && blockIdx.x == 0){
    int a = 0;
    for (int k = 0; k < nb; ++k){ bases[k] = a; a += bsum[k]; }
  }
}

__global__ void scan_off(const int* __restrict__ cnt, const int* __restrict__ bases,
                         int* __restrict__ off, int N2)
{
  int t = threadIdx.x, b = blockIdx.x;
  int i = b * 1024 + t;
  int v = (i < N2) ? cnt[i] : 0;
  int lane = t & 63, wv = t >> 6;
  int x = v;
  #pragma unroll
  for (int o = 1; o < 64; o <<= 1){ int y = __shfl_up(x, o); if (lane >= o) x += y; }
  __shared__ int ws[16];
  if (lane == 63) ws[wv] = x;
  __syncthreads();
  if (t == 0){ int a = 0; for (int k = 0; k < 16; ++k){ int tmp = ws[k]; ws[k] = a; a += tmp; } }
  __syncthreads();
  if (i < N2) off[i] = bases[b] + ws[wv] + x - v;
}

// Build dst-sorted lists: positions [0,NE) = fwd sorted by tail, [NE,2NE) = back by head.
__global__ void scatter_msgs(const int* __restrict__ ht, const int* __restrict__ off,
                             int* __restrict__ cursor, int* __restrict__ perm,
                             int* __restrict__ dstS, int* __restrict__ hS,
                             int n_edges, int n_nodes)
{
  int m = blockIdx.x * 256 + threadIdx.x;
  if (m >= 2 * n_edges) return;
  int e  = (m < n_edges) ? m : m - n_edges;
  int hd = ht[2*e], tl = ht[2*e+1];
  int dst = (m < n_edges) ? tl : hd;
  int oth = (m < n_edges) ? hd : tl;
  int idx = ((m < n_edges) ? 0 : n_nodes) + dst;
  int pos = off[idx] + atomicAdd(&cursor[idx], 1);
  perm[pos] = e; dstS[pos] = dst; hS[pos] = oth;
}

// Barrier-free gather GEMM: no LDS in the K-loop. Wave w owns rows
// [w*16, w*16+16) of the 128-row tile and all 128 cols of its (dir,h) slice.
// A fragments per-lane from E/H (f32 -> bf16 pack); B per-lane from the
// plain bf16 image (L1/L2-resident). LDS used only for the C reduce.
__global__ __launch_bounds__(512, 4) void edge_gemm(
    const float* __restrict__ H, const float* __restrict__ E,
    const int* __restrict__ perm, const int* __restrict__ dstS,
    const int* __restrict__ hS, const unsigned short* __restrict__ Wimg,
    float* __restrict__ agg, int n_edges, int n_nodes)
{
  __shared__ float Cs[128 * 128]; // 64 KB, reduce stage only
  __shared__ int sDst[TE];

  // Bijective XCD-chunked swizzle: 4 q-blocks of a tile on the same XCD.
  const int nwg  = gridDim.x;
  const int orig = blockIdx.x;
  const int xcd  = orig & 7;
  const int lq = nwg >> 3, lr = nwg & 7;
  const int L = (xcd < lr ? xcd * (lq + 1) : lr * (lq + 1) + (xcd - lr) * lq)
                + (orig >> 3);
  const int tile = L >> 2;
  const int dir  = (L >> 1) & 1;
  const int h    = L & 1;
  const int pos0 = tile * TE;      // within dir-list

  const int tid  = threadIdx.x;
  const int lane = tid & 63;
  const int wave = tid >> 6;      // 0..7
  const int rlo  = lane & 15;
  const int khi  = lane >> 4;     // 0..3

  // This lane's A row (all khi groups share the same 16 rows per wave).
  const int row = wave * 16 + rlo;
  {
    int rp  = pos0 + row;
    bool pad = (rp >= n_edges);
    int gpos = dir * n_edges + (pad ? (n_edges - 1) : rp);
    if (khi == 0) sDst[row] = pad ? 0x7fffffff : dstS[gpos];
  }
  int gpos2;
  {
    int rp  = pos0 + row;
    gpos2 = dir * n_edges + ((rp >= n_edges) ? (n_edges - 1) : rp);
  }
  const float* erow = E + (long)perm[gpos2] * D + khi * 8;
  const float* hrow = H + (long)hS[gpos2] * D + khi * 8;

  const char* wq = (const char*)Wimg + (size_t)(dir * 2 + h) * NCHUNK * 16384
                   + rlo * 128 + khi * 16;

  f32x4 acc[8];
  #pragma unroll
  for (int ni = 0; ni < 8; ++ni) acc[ni] = (f32x4){0.f, 0.f, 0.f, 0.f};

  // One chunk: 16 B-fragment loads + 16 MFMA (A0 for k[0..32), A1 for k[32..64)).
  #define CHUNK(c, A0, A1) {                                                 \
    const char* wb = wq + (size_t)(c) * 16384;                               \
    _Pragma("unroll")                                                        \
    for (int ni = 0; ni < 8; ++ni){                                          \
      s16x8 b0 = *(const s16x8*)(wb + ni * 2048);                            \
      acc[ni] = __builtin_amdgcn_mfma_f32_16x16x32_bf16(A0, b0, acc[ni], 0, 0, 0); \
    }                                                                        \
    _Pragma("unroll")                                                        \
    for (int ni = 0; ni < 8; ++ni){                                          \
      s16x8 b1 = *(const s16x8*)(wb + ni * 2048 + 64);                       \
      acc[ni] = __builtin_amdgcn_mfma_f32_16x16x32_bf16(A1, b1, acc[ni], 0, 0, 0); \
    }                                                                        \
  }

  #pragma unroll
  for (int g = 0; g < 4; ++g){
    const float* ec = erow + g * 64;
    const float* hc = hrow + g * 64;
    // part 0: E
    float4 e0 = *(const float4*)(ec);
    float4 e1 = *(const float4*)(ec + 4);
    float4 e2 = *(const float4*)(ec + 32);
    float4 e3 = *(const float4*)(ec + 36);
    {
      s16x8 a0 = pack8(e0, e1), a1 = pack8(e2, e3);
      CHUNK(g * 3 + 0, a0, a1);
    }
    // part 1: E*H
    float4 h0 = *(const float4*)(hc);
    float4 h1 = *(const float4*)(hc + 4);
    float4 h2 = *(const float4*)(hc + 32);
    float4 h3 = *(const float4*)(hc + 36);
    {
      float4 m0 = make_float4(e0.x*h0.x, e0.y*h0.y, e0.z*h0.z, e0.w*h0.w);
      float4 m1 = make_float4(e1.x*h1.x, e1.y*h1.y, e1.z*h1.z, e1.w*h1.w);
      float4 m2 = make_float4(e2.x*h2.x, e2.y*h2.y, e2.z*h2.z, e2.w*h2.w);
      float4 m3 = make_float4(e3.x*h3.x, e3.y*h3.y, e3.z*h3.z, e3.w*h3.w);
      s16x8 a0 = pack8(m0, m1), a1 = pack8(m2, m3);
      CHUNK(g * 3 + 1, a0, a1);
    }
    // part 2: H
    {
      s16x8 a0 = pack8(h0, h1), a1 = pack8(h2, h3);
      CHUNK(g * 3 + 2, a0, a1);
    }
  }
  #undef CHUNK

  // ---- Epilogue: C -> LDS (bank-rotated), segmented run-reduce ----
  #pragma unroll
  for (int ni = 0; ni < 8; ++ni)
    #pragma unroll
    for (int r = 0; r < 4; ++r){
      int rw = wave * 16 + khi * 4 + r;
      int col = ni * 16 + rlo;
      int cw = (col + ((rw & 7) << 2)) & 127;
      Cs[rw * 128 + cw] = acc[ni][r];
    }
  __syncthreads();

  {
    const int col = tid & 127;
    const int q   = tid >> 7;          // 4 row-quarters
    int r0 = q << 5;
    if (q > 0 && sDst[r0] == sDst[r0 - 1]){
      int pd = sDst[r0 - 1];
      int rcap = (q << 5) + 32;
      while (r0 < rcap && sDst[r0] == pd) r0++;
    }
    const int rend = (q << 5) + 32;
    for (int r = r0; r < rend; ){
      int d = sDst[r];
      float s = 0.f;
      int rr = r;
      while (rr < 128 && sDst[rr] == d){
        s += Cs[rr * 128 + ((col + ((rr & 7) << 2)) & 127)];
        rr++;
      }
      if (d < n_nodes)
        atomicAdd(agg + (long)d * D + h * NB + col, s);
      r = rr;
    }
  }
}

__global__ __launch_bounds__(256) void finish(
    const float* __restrict__ agg, const int* __restrict__ cnt_i,
    const float* __restrict__ H, const float* __restrict__ bias_f,
    const float* __restrict__ bias_b, const float* __restrict__ gamma,
    const float* __restrict__ beta, float* __restrict__ out, int n_nodes)
{
  const int n = blockIdx.x;
  const int j = threadIdx.x;
  int cf = cnt_i[n], cb = cnt_i[n_nodes + n];
  float c = (float)(cf + cb); c = c < 1.f ? 1.f : c;
  float a = (agg[(long)n * D + j] + (float)cf * bias_f[j] + (float)cb * bias_b[j]) / c;
  float x = (a > 0.f ? a : LEAKY * a) + H[(long)n * D + j];
  float s1 = x, s2 = x * x;
  #pragma unroll
  for (int off = 32; off > 0; off >>= 1){
    s1 += __shfl_xor(s1, off);
    s2 += __shfl_xor(s2, off);
  }
  __shared__ float rs[8];
  if ((j & 63) == 0){ rs[j >> 6] = s1; rs[4 + (j >> 6)] = s2; }
  __syncthreads();
  float t1 = rs[0] + rs[1] + rs[2] + rs[3];
  float t2 = rs[4] + rs[5] + rs[6] + rs[7];
  float mu = t1 * (1.f / D);
  float var = t2 * (1.f / D) - mu * mu;
  float r = rsqrtf(var + EPS);
  out[(long)n * D + j] = (x - mu) * r * gamma[j] + beta[j];
}

extern "C" void kernel_launch(void* const* d_in, const int* in_sizes, int n_in,
                              void* d_out, int out_size, void* d_ws, size_t ws_size,
                              hipStream_t stream)
{
  const float* H      = (const float*)d_in[0];
  const float* E      = (const float*)d_in[1];
  const int*   ht     = (const int*)d_in[2];
  const float* W_fwd  = (const float*)d_in[3];
  const float* b_fwd  = (const float*)d_in[4];
  const float* W_back = (const float*)d_in[5];
  const float* b_back = (const float*)d_in[6];
  const float* gamma  = (const float*)d_in[7];
  const float* beta   = (const float*)d_in[8];
  float* out = (float*)d_out;

  const int n_nodes = in_sizes[0] / D;
  const int n_edges = in_sizes[2] / 2;
  const int N2 = 2 * n_nodes;
  const int NM = 2 * n_edges;

  char* p = (char*)d_ws;
  float* agg    = (float*)p;  p += (size_t)n_nodes * D * 4;
  int*   cnt_i  = (int*)p;    p += (size_t)N2 * 4;
  int*   cursor = (int*)p;    p += (size_t)N2 * 4;
  size_t zbytes = (size_t)(p - (char*)d_ws);          // agg + cnt + cursor
  int*   off    = (int*)p;    p += (size_t)N2 * 4;
  int*   bsum   = (int*)p;    p += 128 * 4;
  int*   bases  = (int*)p;    p += 128 * 4;
  int*   perm   = (int*)p;    p += (size_t)NM * 4;
  int*   dstS   = (int*)p;    p += (size_t)NM * 4;
  int*   hS     = (int*)p;    p += (size_t)NM * 4;
  unsigned short* Wimg = (unsigned short*)p;

  const int nscan = (N2 + 1023) / 1024;

  hipMemsetAsync(d_ws, 0, zbytes, stream);
  prep_w<<<(2 * 2 * NCHUNK * NB * BK) / 256, 256, 0, stream>>>(W_fwd, W_back, Wimg);
  count2<<<(n_edges + 255) / 256, 256, 0, stream>>>(ht, cnt_i, n_edges, n_nodes);
  scan_sums<<<nscan, 1024, 0, stream>>>(cnt_i, bsum, N2);
  scan_bases<<<1, 64, 0, stream>>>(bsum, bases, nscan);
  scan_off<<<nscan, 1024, 0, stream>>>(cnt_i, bases, off, N2);
  scatter_msgs<<<(NM + 255) / 256, 256, 0, stream>>>(ht, off, cursor, perm, dstS, hS,
                                                     n_edges, n_nodes);
  const int ntiles = (n_edges + TE - 1) / TE;
  edge_gemm<<<ntiles * 4, 512, 0, stream>>>(H, E, perm, dstS, hS, Wimg, agg,
                                            n_edges, n_nodes);
  finish<<<n_nodes, 256, 0, stream>>>(agg, cnt_i, H, b_fwd, b_back, gamma, beta,
                                      out, n_nodes);
}

// Round 10
// 553.354 us; speedup vs baseline: 3.0245x; 3.0245x over previous
//
#include <hip/hip_runtime.h>
#include <hip/hip_bf16.h>

#define D 256
#define TE 128         // messages per tile
#define NB 128         // output cols per block (colhalf)
#define BK 64          // K-chunk
#define NCHUNK 12      // 4 groups x [E | E*H | H]
#define LEAKY 0.01f
#define EPS 1e-5f

typedef float f32x4 __attribute__((ext_vector_type(4)));
typedef short s16x8 __attribute__((ext_vector_type(8)));

__device__ __forceinline__ unsigned short f2bf(float f){
  union { float f; unsigned int u; } v; v.f = f;
  unsigned int u = v.u;
  return (unsigned short)((u + 0x7fffu + ((u >> 16) & 1u)) >> 16);
}
__device__ __forceinline__ unsigned int pack2(float a, float b){
  return (unsigned int)f2bf(a) | ((unsigned int)f2bf(b) << 16);
}

// Fragment-major bf16 image of folded weights:
// tile t = (dir*2+h)*12 + c (16 KB each); within: [ks][j][lane][e]
// (e=0..7 bf16, lane=0..63, j=coltile 0..7, ks=0..1).
// Element meaning: col = h*128 + j*16 + (lane&15),
//                  k_local = ks*32 + (lane>>4)*8 + e,  x = g*64 + k_local.
// A wave's B-fragment load is then 64 lanes x 16B CONTIGUOUS (1 KB).
__global__ void prep_w(const float* __restrict__ Wf, const float* __restrict__ Wb,
                       unsigned short* __restrict__ Wimg)
{
  int i = blockIdx.x * 256 + threadIdx.x;       // 2*2*12*8192 = 393216
  int inner = i & 8191;
  int t = i >> 13;                              // (dir*2+h)*12 + c
  int c = t % 12;
  int q = t / 12;
  int dir = q >> 1, h = q & 1;
  int g = c / 3, part = c - g * 3;
  int e    = inner & 7;
  int lane = (inner >> 3) & 63;
  int j    = (inner >> 9) & 7;
  int ks   = inner >> 12;
  int kloc = ks * 32 + (lane >> 4) * 8 + e;
  int x = g * 64 + kloc;                        // original feature index
  int col = h * NB + j * 16 + (lane & 15);
  const float* row = (dir ? Wb : Wf) + (long)col * (4 * D);
  // raw = [Hh | E | Hh+E | Hh*E]:
  float v;
  if (part == 0)      v = row[256 + x] + row[512 + x];   // E coeff
  else if (part == 1) v = row[768 + x];                  // Hh*E coeff
  else                v = row[x] + row[512 + x];         // Hh coeff
  Wimg[(size_t)t * 8192 + inner] = f2bf(v);
}

// Per-dir dst histogram: cnt[0..n) = fwd (dst=tail), cnt[n..2n) = back (dst=head)
__global__ void count2(const int* __restrict__ ht, int* __restrict__ cnt,
                       int n_edges, int n_nodes)
{
  int e = blockIdx.x * 256 + threadIdx.x;
  if (e < n_edges){
    atomicAdd(&cnt[ht[2*e+1]], 1);
    atomicAdd(&cnt[n_nodes + ht[2*e]], 1);
  }
}

__global__ void scan_sums(const int* __restrict__ cnt, int* __restrict__ bsum, int N2)
{
  int t = threadIdx.x, b = blockIdx.x;
  int i = b * 1024 + t;
  int v = (i < N2) ? cnt[i] : 0;
  #pragma unroll
  for (int o = 32; o > 0; o >>= 1) v += __shfl_down(v, o);
  __shared__ int red[16];
  int lane = t & 63, wv = t >> 6;
  if (lane == 0) red[wv] = v;
  __syncthreads();
  if (t == 0){ int s = 0; for (int k = 0; k < 16; ++k) s += red[k]; bsum[b] = s; }
}

__global__ void scan_bases(const int* __restrict__ bsum, int* __restrict__ bases, int nb)
{
  if (threadIdx.x == 0 && blockIdx.x == 0){
    int a = 0;
    for (int k = 0; k < nb; ++k){ bases[k] = a; a += bsum[k]; }
  }
}

__global__ void scan_off(const int* __restrict__ cnt, const int* __restrict__ bases,
                         int* __restrict__ off, int N2)
{
  int t = threadIdx.x, b = blockIdx.x;
  int i = b * 1024 + t;
  int v = (i < N2) ? cnt[i] : 0;
  int lane = t & 63, wv = t >> 6;
  int x = v;
  #pragma unroll
  for (int o = 1; o < 64; o <<= 1){ int y = __shfl_up(x, o); if (lane >= o) x += y; }
  __shared__ int ws[16];
  if (lane == 63) ws[wv] = x;
  __syncthreads();
  if (t == 0){ int a = 0; for (int k = 0; k < 16; ++k){ int tmp = ws[k]; ws[k] = a; a += tmp; } }
  __syncthreads();
  if (i < N2) off[i] = bases[b] + ws[wv] + x - v;
}

// Build dst-sorted lists: positions [0,NE) = fwd sorted by tail, [NE,2NE) = back by head.
__global__ void scatter_msgs(const int* __restrict__ ht, const int* __restrict__ off,
                             int* __restrict__ cursor, int* __restrict__ perm,
                             int* __restrict__ dstS, int* __restrict__ hS,
                             int n_edges, int n_nodes)
{
  int m = blockIdx.x * 256 + threadIdx.x;
  if (m >= 2 * n_edges) return;
  int e  = (m < n_edges) ? m : m - n_edges;
  int hd = ht[2*e], tl = ht[2*e+1];
  int dst = (m < n_edges) ? tl : hd;
  int oth = (m < n_edges) ? hd : tl;
  int idx = ((m < n_edges) ? 0 : n_nodes) + dst;
  int pos = off[idx] + atomicAdd(&cursor[idx], 1);
  perm[pos] = e; dstS[pos] = dst; hS[pos] = oth;
}

// A staged in LDS (shared gather, double-buffered, XOR-swizzled), B per-lane
// in registers from the fragment-major image (coalesced 1KB/load, L2-hot).
// K-loop barriers are lgkmcnt-only (raw s_barrier) — no vmcnt drain, so the
// depth-2/3 A-gather prefetch stays in flight across barriers.
__global__ __launch_bounds__(512, 4) void edge_gemm(
    const float* __restrict__ H, const float* __restrict__ E,
    const int* __restrict__ perm, const int* __restrict__ dstS,
    const int* __restrict__ hS, const unsigned short* __restrict__ Wimg,
    float* __restrict__ agg, int n_edges, int n_nodes)
{
  __shared__ float Cs[128 * 128];  // 64 KB; first 32 KB doubles as A dbuf
  __shared__ int sDst[TE];
  char (*sAl)[16384] = (char(*)[16384])Cs;

  // Bijective XCD-chunked swizzle: 4 q-blocks of a tile on the same XCD.
  const int nwg  = gridDim.x;
  const int orig = blockIdx.x;
  const int xcd  = orig & 7;
  const int lq = nwg >> 3, lr = nwg & 7;
  const int L = (xcd < lr ? xcd * (lq + 1) : lr * (lq + 1) + (xcd - lr) * lq)
                + (orig >> 3);
  const int tile = L >> 2;
  const int dir  = (L >> 1) & 1;
  const int h    = L & 1;
  const int pos0 = tile * TE;      // within dir-list

  const int tid  = threadIdx.x;
  const int lane = tid & 63;
  const int wave = tid >> 6;      // 0..7

  // A staging: thread -> 4 rows x 4 cols. cg = col group, rows rg*4+i.
  const int cg = tid & 15;
  const int rg = tid >> 4;        // 0..31
  const float* eptr[4]; const float* hptr[4];
  #pragma unroll
  for (int i = 0; i < 4; ++i){
    int row = rg * 4 + i;
    int rp  = pos0 + row;
    bool pad = (rp >= n_edges);
    int gpos = dir * n_edges + (pad ? (n_edges - 1) : rp);
    eptr[i] = E + (long)perm[gpos] * D;
    hptr[i] = H + (long)hS[gpos] * D;
    if (cg == 0) sDst[row] = pad ? 0x7fffffff : dstS[gpos];
  }
  __syncthreads();

  const char* wqB = (const char*)Wimg + (size_t)(dir * 2 + h) * NCHUNK * 16384
                    + lane * 16;

  f32x4 acc[4][2];
  #pragma unroll
  for (int mi = 0; mi < 4; ++mi)
    #pragma unroll
    for (int ni = 0; ni < 2; ++ni)
      acc[mi][ni] = (f32x4){0.f, 0.f, 0.f, 0.f};

  float4 sl0[4], sl1[4];          // A reg slots: A(x) -> slot (x&1)
  float4 Ev[4];                   // persistent E regs across a part-triplet
  s16x8 bfr[4];                   // B frags for current chunk: [ks][ni]

  const int rlo = lane & 15;
  const int khi = lane >> 4;
  const int wm = wave >> 2;       // 0..1: 64-row slab
  const int wn = wave & 3;        // 0..3: 32-col slab

  #define ISSUE_A(c) {                                                       \
    const int g_ = (c) / 3, part_ = (c) % 3;                                 \
    float4* dst_ = ((c) & 1) ? sl1 : sl0;                                    \
    _Pragma("unroll")                                                        \
    for (int i = 0; i < 4; ++i)                                              \
      dst_[i] = *(const float4*)((part_ == 0 ? eptr[i] : hptr[i])            \
                                 + g_ * 64 + cg * 4);                        \
  }

  #define WRITE_A(c, buf) {                                                  \
    const int part_ = (c) % 3;                                               \
    float4* src_ = ((c) & 1) ? sl1 : sl0;                                    \
    _Pragma("unroll")                                                        \
    for (int i = 0; i < 4; ++i){                                             \
      int row = rg * 4 + i;                                                  \
      float4 v;                                                              \
      if (part_ == 0){ Ev[i] = src_[i]; v = src_[i]; }                       \
      else if (part_ == 1) v = make_float4(Ev[i].x*src_[i].x,                \
          Ev[i].y*src_[i].y, Ev[i].z*src_[i].z, Ev[i].w*src_[i].w);          \
      else v = src_[i];                                                      \
      uint2 w; w.x = pack2(v.x, v.y); w.y = pack2(v.z, v.w);                 \
      int off = (row * 128 + cg * 8) ^ ((row & 7) << 4);                     \
      *(uint2*)(&sAl[buf][off]) = w;                                         \
    }                                                                        \
  }

  // 4 coalesced 16B loads: B frags (ks 0/1) x (ni 0/1) for this wave's cols.
  #define LOAD_B(c) {                                                        \
    const char* bb = wqB + (size_t)(c) * 16384;                              \
    bfr[0] = *(const s16x8*)(bb + (wn * 2 + 0) * 1024);                      \
    bfr[1] = *(const s16x8*)(bb + (wn * 2 + 1) * 1024);                      \
    bfr[2] = *(const s16x8*)(bb + 8192 + (wn * 2 + 0) * 1024);               \
    bfr[3] = *(const s16x8*)(bb + 8192 + (wn * 2 + 1) * 1024);               \
  }

  #define KBAR() { asm volatile("s_waitcnt lgkmcnt(0)" ::: "memory");        \
                   __builtin_amdgcn_s_barrier(); }

  // ---- Prologue ----
  ISSUE_A(0);
  ISSUE_A(1);
  WRITE_A(0, 0);                  // compiler auto-waits A(0)
  ISSUE_A(2);
  LOAD_B(0);
  KBAR();

  // ---- Main loop. Top-of-iter c: sAl[c&1] ready; A(c+1) regs arrived;
  // A(c+2)[,A(c+3)] in flight; bfr holds B(c).
  #pragma unroll
  for (int c = 0; c < NCHUNK; ++c){
    const int cur = c & 1;
    if (c + 1 < NCHUNK){
      WRITE_A(c + 1, cur ^ 1);     // regs -> other buf (auto vmcnt wait)
    }
    if (c + 3 < NCHUNK){
      ISSUE_A(c + 3);              // into slot just freed
    }
    #pragma unroll
    for (int ks = 0; ks < 2; ++ks){
      const int kb = (ks * 32 + khi * 8) * 2;
      s16x8 af[4];
      #pragma unroll
      for (int mi = 0; mi < 4; ++mi){
        int row = wm * 64 + mi * 16 + rlo;
        af[mi] = *(const s16x8*)(&sAl[cur][(row * 128 + kb) ^ ((row & 7) << 4)]);
      }
      #pragma unroll
      for (int mi = 0; mi < 4; ++mi)
        #pragma unroll
        for (int ni = 0; ni < 2; ++ni)
          acc[mi][ni] = __builtin_amdgcn_mfma_f32_16x16x32_bf16(
              af[mi], bfr[ks * 2 + ni], acc[mi][ni], 0, 0, 0);
    }
    if (c + 1 < NCHUNK){
      LOAD_B(c + 1);               // next B; auto-waited at next MFMA
      KBAR();                      // lgkm-only: A prefetch stays in flight
    }
  }
  #undef ISSUE_A
  #undef WRITE_A
  #undef LOAD_B
  #undef KBAR

  // ---- Epilogue: C -> LDS (bank-rotated), segmented run-reduce ----
  __syncthreads();                 // all MFMA LDS reads done; Cs reusable
  #pragma unroll
  for (int mi = 0; mi < 4; ++mi)
    #pragma unroll
    for (int ni = 0; ni < 2; ++ni)
      #pragma unroll
      for (int r = 0; r < 4; ++r){
        int rw = wm * 64 + mi * 16 + khi * 4 + r;
        int col = wn * 32 + ni * 16 + rlo;
        int cw = (col + ((rw & 7) << 2)) & 127;
        Cs[rw * 128 + cw] = acc[mi][ni][r];
      }
  __syncthreads();

  {
    const int col = tid & 127;
    const int q   = tid >> 7;          // 4 row-quarters
    int r0 = q << 5;
    if (q > 0 && sDst[r0] == sDst[r0 - 1]){
      int pd = sDst[r0 - 1];
      int rcap = (q << 5) + 32;
      while (r0 < rcap && sDst[r0] == pd) r0++;
    }
    const int rend = (q << 5) + 32;
    for (int r = r0; r < rend; ){
      int d = sDst[r];
      float s = 0.f;
      int rr = r;
      while (rr < 128 && sDst[rr] == d){
        s += Cs[rr * 128 + ((col + ((rr & 7) << 2)) & 127)];
        rr++;
      }
      if (d < n_nodes)
        atomicAdd(agg + (long)d * D + h * NB + col, s);
      r = rr;
    }
  }
}

__global__ __launch_bounds__(256) void finish(
    const float* __restrict__ agg, const int* __restrict__ cnt_i,
    const float* __restrict__ H, const float* __restrict__ bias_f,
    const float* __restrict__ bias_b, const float* __restrict__ gamma,
    const float* __restrict__ beta, float* __restrict__ out, int n_nodes)
{
  const int n = blockIdx.x;
  const int j = threadIdx.x;
  int cf = cnt_i[n], cb = cnt_i[n_nodes + n];
  float c = (float)(cf + cb); c = c < 1.f ? 1.f : c;
  float a = (agg[(long)n * D + j] + (float)cf * bias_f[j] + (float)cb * bias_b[j]) / c;
  float x = (a > 0.f ? a : LEAKY * a) + H[(long)n * D + j];
  float s1 = x, s2 = x * x;
  #pragma unroll
  for (int off = 32; off > 0; off >>= 1){
    s1 += __shfl_xor(s1, off);
    s2 += __shfl_xor(s2, off);
  }
  __shared__ float rs[8];
  if ((j & 63) == 0){ rs[j >> 6] = s1; rs[4 + (j >> 6)] = s2; }
  __syncthreads();
  float t1 = rs[0] + rs[1] + rs[2] + rs[3];
  float t2 = rs[4] + rs[5] + rs[6] + rs[7];
  float mu = t1 * (1.f / D);
  float var = t2 * (1.f / D) - mu * mu;
  float r = rsqrtf(var + EPS);
  out[(long)n * D + j] = (x - mu) * r * gamma[j] + beta[j];
}

extern "C" void kernel_launch(void* const* d_in, const int* in_sizes, int n_in,
                              void* d_out, int out_size, void* d_ws, size_t ws_size,
                              hipStream_t stream)
{
  const float* H      = (const float*)d_in[0];
  const float* E      = (const float*)d_in[1];
  const int*   ht     = (const int*)d_in[2];
  const float* W_fwd  = (const float*)d_in[3];
  const float* b_fwd  = (const float*)d_in[4];
  const float* W_back = (const float*)d_in[5];
  const float* b_back = (const float*)d_in[6];
  const float* gamma  = (const float*)d_in[7];
  const float* beta   = (const float*)d_in[8];
  float* out = (float*)d_out;

  const int n_nodes = in_sizes[0] / D;
  const int n_edges = in_sizes[2] / 2;
  const int N2 = 2 * n_nodes;
  const int NM = 2 * n_edges;

  char* p = (char*)d_ws;
  float* agg    = (float*)p;  p += (size_t)n_nodes * D * 4;
  int*   cnt_i  = (int*)p;    p += (size_t)N2 * 4;
  int*   cursor = (int*)p;    p += (size_t)N2 * 4;
  size_t zbytes = (size_t)(p - (char*)d_ws);          // agg + cnt + cursor
  int*   off    = (int*)p;    p += (size_t)N2 * 4;
  int*   bsum   = (int*)p;    p += 128 * 4;
  int*   bases  = (int*)p;    p += 128 * 4;
  int*   perm   = (int*)p;    p += (size_t)NM * 4;
  int*   dstS   = (int*)p;    p += (size_t)NM * 4;
  int*   hS     = (int*)p;    p += (size_t)NM * 4;
  unsigned short* Wimg = (unsigned short*)p;

  const int nscan = (N2 + 1023) / 1024;

  hipMemsetAsync(d_ws, 0, zbytes, stream);
  prep_w<<<(2 * 2 * NCHUNK * 8192) / 256, 256, 0, stream>>>(W_fwd, W_back, Wimg);
  count2<<<(n_edges + 255) / 256, 256, 0, stream>>>(ht, cnt_i, n_edges, n_nodes);
  scan_sums<<<nscan, 1024, 0, stream>>>(cnt_i, bsum, N2);
  scan_bases<<<1, 64, 0, stream>>>(bsum, bases, nscan);
  scan_off<<<nscan, 1024, 0, stream>>>(cnt_i, bases, off, N2);
  scatter_msgs<<<(NM + 255) / 256, 256, 0, stream>>>(ht, off, cursor, perm, dstS, hS,
                                                     n_edges, n_nodes);
  const int ntiles = (n_edges + TE - 1) / TE;
  edge_gemm<<<ntiles * 4, 512, 0, stream>>>(H, E, perm, dstS, hS, Wimg, agg,
                                            n_edges, n_nodes);
  finish<<<n_nodes, 256, 0, stream>>>(agg, cnt_i, H, b_fwd, b_back, gamma, beta,
                                      out, n_nodes);
}

// Round 11
// 497.231 us; speedup vs baseline: 3.3659x; 1.1129x over previous
//
#include <hip/hip_runtime.h>
#include <hip/hip_bf16.h>

#define D 256
#define TE 128         // messages per tile
#define NB 128         // output cols per block (colhalf)
#define BK 64          // K-chunk
#define NCHUNK 12      // 4 groups x [E | E*H | H]
#define LEAKY 0.01f
#define EPS 1e-5f

typedef float f32x4 __attribute__((ext_vector_type(4)));
typedef short s16x8 __attribute__((ext_vector_type(8)));

#define GLL16(g, l) __builtin_amdgcn_global_load_lds(                      \
    (const __attribute__((address_space(1))) unsigned int*)(g),            \
    (__attribute__((address_space(3))) unsigned int*)(l), 16, 0, 0)

__device__ __forceinline__ unsigned short f2bf(float f){
  union { float f; unsigned int u; } v; v.f = f;
  unsigned int u = v.u;
  return (unsigned short)((u + 0x7fffu + ((u >> 16) & 1u)) >> 16);
}
// HW pack: D.lo = bf16(lo), D.hi = bf16(hi), RNE — 1 VALU op vs ~12 emulated.
__device__ __forceinline__ unsigned int cvtpk(float lo, float hi){
  unsigned int r;
  asm("v_cvt_pk_bf16_f32 %0, %1, %2" : "=v"(r) : "v"(lo), "v"(hi));
  return r;
}

// Pre-swizzled LDS images of folded weights, per (dir, colhalf, chunk).
// K reorder: group g in 0..3, parts [E_g | (E*H)_g | H_g], chunk c = g*3+part.
// Image tile t = (dir*2+h)*12 + c (16 KB): boff = (j*128 + k*2) ^ ((j&7)<<4).
__global__ void prep_w(const float* __restrict__ Wf, const float* __restrict__ Wb,
                       unsigned short* __restrict__ Wimg)
{
  int i = blockIdx.x * 256 + threadIdx.x;       // 2*2*12*128*64 = 393216
  int inner = i & 8191;                         // j*64 + k
  int t = i >> 13;                              // (dir*2+h)*12 + c
  int c = t % 12;
  int q = t / 12;
  int dir = q >> 1, h = q & 1;
  int g = c / 3, part = c - g * 3;
  int j = inner >> 6, k = inner & 63;
  int x = g * 64 + k;                           // original feature index
  const float* row = (dir ? Wb : Wf) + (long)(h * NB + j) * (4 * D);
  // raw = [Hh | E | Hh+E | Hh*E]:
  float v;
  if (part == 0)      v = row[256 + x] + row[512 + x];   // E coeff
  else if (part == 1) v = row[768 + x];                  // Hh*E coeff
  else                v = row[x] + row[512 + x];         // Hh coeff
  int boff = (j * 128 + k * 2) ^ ((j & 7) << 4);
  *(unsigned short*)((char*)Wimg + (size_t)t * 16384 + boff) = f2bf(v);
}

// Per-dir dst histogram: cnt[0..n) = fwd (dst=tail), cnt[n..2n) = back (dst=head)
__global__ void count2(const int* __restrict__ ht, int* __restrict__ cnt,
                       int n_edges, int n_nodes)
{
  int e = blockIdx.x * 256 + threadIdx.x;
  if (e < n_edges){
    atomicAdd(&cnt[ht[2*e+1]], 1);
    atomicAdd(&cnt[n_nodes + ht[2*e]], 1);
  }
}

__global__ void scan_sums(const int* __restrict__ cnt, int* __restrict__ bsum, int N2)
{
  int t = threadIdx.x, b = blockIdx.x;
  int i = b * 1024 + t;
  int v = (i < N2) ? cnt[i] : 0;
  #pragma unroll
  for (int o = 32; o > 0; o >>= 1) v += __shfl_down(v, o);
  __shared__ int red[16];
  int lane = t & 63, wv = t >> 6;
  if (lane == 0) red[wv] = v;
  __syncthreads();
  if (t == 0){ int s = 0; for (int k = 0; k < 16; ++k) s += red[k]; bsum[b] = s; }
}

__global__ void scan_bases(const int* __restrict__ bsum, int* __restrict__ bases, int nb)
{
  if (threadIdx.x == 0 && blockIdx.x == 0){
    int a = 0;
    for (int k = 0; k < nb; ++k){ bases[k] = a; a += bsum[k]; }
  }
}

__global__ void scan_off(const int* __restrict__ cnt, const int* __restrict__ bases,
                         int* __restrict__ off, int N2)
{
  int t = threadIdx.x, b = blockIdx.x;
  int i = b * 1024 + t;
  int v = (i < N2) ? cnt[i] : 0;
  int lane = t & 63, wv = t >> 6;
  int x = v;
  #pragma unroll
  for (int o = 1; o < 64; o <<= 1){ int y = __shfl_up(x, o); if (lane >= o) x += y; }
  __shared__ int ws[16];
  if (lane == 63) ws[wv] = x;
  __syncthreads();
  if (t == 0){ int a = 0; for (int k = 0; k < 16; ++k){ int tmp = ws[k]; ws[k] = a; a += tmp; } }
  __syncthreads();
  if (i < N2) off[i] = bases[b] + ws[wv] + x - v;
}

// Build dst-sorted lists: positions [0,NE) = fwd sorted by tail, [NE,2NE) = back by head.
__global__ void scatter_msgs(const int* __restrict__ ht, const int* __restrict__ off,
                             int* __restrict__ cursor, int* __restrict__ perm,
                             int* __restrict__ dstS, int* __restrict__ hS,
                             int n_edges, int n_nodes)
{
  int m = blockIdx.x * 256 + threadIdx.x;
  if (m >= 2 * n_edges) return;
  int e  = (m < n_edges) ? m : m - n_edges;
  int hd = ht[2*e], tl = ht[2*e+1];
  int dst = (m < n_edges) ? tl : hd;
  int oth = (m < n_edges) ? hd : tl;
  int idx = ((m < n_edges) ? 0 : n_nodes) + dst;
  int pos = off[idx] + atomicAdd(&cursor[idx], 1);
  perm[pos] = e; dstS[pos] = dst; hS[pos] = oth;
}

__global__ __launch_bounds__(512, 4) void edge_gemm(
    const float* __restrict__ H, const float* __restrict__ E,
    const int* __restrict__ perm, const int* __restrict__ dstS,
    const int* __restrict__ hS, const unsigned short* __restrict__ Wimg,
    float* __restrict__ agg, int n_edges, int n_nodes)
{
  __shared__ char smem[65536];     // A dbuf (0..32K) + B dbuf (32K..64K); C reuse
  __shared__ int sDst[TE];
  char (*sAl)[16384] = (char(*)[16384])smem;
  char (*sBl)[16384] = (char(*)[16384])(smem + 32768);

  // Bijective XCD-chunked swizzle: 4 q-blocks of a tile on the same XCD.
  const int nwg  = gridDim.x;
  const int orig = blockIdx.x;
  const int xcd  = orig & 7;
  const int lq = nwg >> 3, lr = nwg & 7;
  const int L = (xcd < lr ? xcd * (lq + 1) : lr * (lq + 1) + (xcd - lr) * lq)
                + (orig >> 3);
  const int tile = L >> 2;
  const int dir  = (L >> 1) & 1;
  const int h    = L & 1;
  const int pos0 = tile * TE;      // within dir-list

  const int tid  = threadIdx.x;
  const int lane = tid & 63;
  const int wave = tid >> 6;      // 0..7

  // A staging: thread -> 4 rows x 4 cols. cg = col group, rows rg*4+i.
  const int cg = tid & 15;
  const int rg = tid >> 4;        // 0..31
  const float* eptr[4]; const float* hptr[4];
  #pragma unroll
  for (int i = 0; i < 4; ++i){
    int row = rg * 4 + i;
    int rp  = pos0 + row;
    bool pad = (rp >= n_edges);
    int gpos = dir * n_edges + (pad ? (n_edges - 1) : rp);
    eptr[i] = E + (long)perm[gpos] * D;
    hptr[i] = H + (long)hS[gpos] * D;
    if (cg == 0) sDst[row] = pad ? 0x7fffffff : dstS[gpos];
  }
  __syncthreads();

  const char* wq = (const char*)Wimg + (size_t)(dir * 2 + h) * NCHUNK * 16384;

  f32x4 acc[4][2];
  #pragma unroll
  for (int mi = 0; mi < 4; ++mi)
    #pragma unroll
    for (int ni = 0; ni < 2; ++ni)
      acc[mi][ni] = (f32x4){0.f, 0.f, 0.f, 0.f};

  float4 sl0[4], sl1[4];          // A reg slots: A(x) -> slot (x&1)
  float4 Ev[4];                   // persistent E regs across a part-triplet

  const int rlo = lane & 15;
  const int khi = lane >> 4;
  const int wm = wave >> 2;       // 0..1: 64-row slab
  const int wn = wave & 3;        // 0..3: 32-col slab

  #define ISSUE_A(c) {                                                       \
    const int g_ = (c) / 3, part_ = (c) % 3;                                 \
    float4* dst_ = ((c) & 1) ? sl1 : sl0;                                    \
    _Pragma("unroll")                                                        \
    for (int i = 0; i < 4; ++i)                                              \
      dst_[i] = *(const float4*)((part_ == 0 ? eptr[i] : hptr[i])            \
                                 + g_ * 64 + cg * 4);                        \
  }

  #define WRITE_A(c, buf) {                                                  \
    const int part_ = (c) % 3;                                               \
    float4* src_ = ((c) & 1) ? sl1 : sl0;                                    \
    _Pragma("unroll")                                                        \
    for (int i = 0; i < 4; ++i){                                             \
      int row = rg * 4 + i;                                                  \
      float4 v;                                                              \
      if (part_ == 0){ Ev[i] = src_[i]; v = src_[i]; }                       \
      else if (part_ == 1) v = make_float4(Ev[i].x*src_[i].x,                \
          Ev[i].y*src_[i].y, Ev[i].z*src_[i].z, Ev[i].w*src_[i].w);          \
      else v = src_[i];                                                      \
      uint2 w; w.x = cvtpk(v.x, v.y); w.y = cvtpk(v.z, v.w);                 \
      int off = (row * 128 + cg * 8) ^ ((row & 7) << 4);                     \
      *(uint2*)(&sAl[buf][off]) = w;                                         \
    }                                                                        \
  }

  #define STAGE_B(c, buf) {                                                  \
    const char* srcb = wq + (size_t)(c) * 16384 + wave * 2048 + lane * 16;   \
    char* db = &sBl[buf][wave * 2048];                                       \
    GLL16(srcb,        db);                                                  \
    GLL16(srcb + 1024, db + 1024);                                           \
  }

  // ---- Prologue ----
  ISSUE_A(0);
  ISSUE_A(1);
  STAGE_B(0, 0);
  WRITE_A(0, 0);
  ISSUE_A(2);
  __syncthreads();

  // ---- Main loop (R7-proven structure) ----
  #pragma unroll
  for (int c = 0; c < NCHUNK; ++c){
    const int cur = c & 1;
    if (c + 1 < NCHUNK){
      STAGE_B(c + 1, cur ^ 1);
      WRITE_A(c + 1, cur ^ 1);
    }
    if (c + 3 < NCHUNK){
      ISSUE_A(c + 3);
    }
    #pragma unroll
    for (int ks = 0; ks < 2; ++ks){
      const int kb = (ks * 32 + khi * 8) * 2;
      s16x8 af[4], bfr[2];
      #pragma unroll
      for (int mi = 0; mi < 4; ++mi){
        int row = wm * 64 + mi * 16 + rlo;
        af[mi] = *(const s16x8*)(&sAl[cur][(row * 128 + kb) ^ ((row & 7) << 4)]);
      }
      #pragma unroll
      for (int ni = 0; ni < 2; ++ni){
        int col = wn * 32 + ni * 16 + rlo;
        bfr[ni] = *(const s16x8*)(&sBl[cur][(col * 128 + kb) ^ ((col & 7) << 4)]);
      }
      #pragma unroll
      for (int mi = 0; mi < 4; ++mi)
        #pragma unroll
        for (int ni = 0; ni < 2; ++ni)
          acc[mi][ni] = __builtin_amdgcn_mfma_f32_16x16x32_bf16(
              af[mi], bfr[ni], acc[mi][ni], 0, 0, 0);
    }
    if (c + 1 < NCHUNK) __syncthreads();
  }
  #undef ISSUE_A
  #undef WRITE_A
  #undef STAGE_B

  // ---- Epilogue: C -> LDS, segmented run-reduce over dst-sorted rows ----
  __syncthreads();                 // all MFMA LDS reads done; smem reusable
  float* Cs = (float*)smem;        // [128][128], bank-rotated by row
  #pragma unroll
  for (int mi = 0; mi < 4; ++mi)
    #pragma unroll
    for (int ni = 0; ni < 2; ++ni)
      #pragma unroll
      for (int r = 0; r < 4; ++r){
        int row = wm * 64 + mi * 16 + khi * 4 + r;
        int col = wn * 32 + ni * 16 + rlo;
        int cw = (col + ((row & 7) << 2)) & 127;
        Cs[row * 128 + cw] = acc[mi][ni][r];
      }
  __syncthreads();

  {
    const int col = tid & 127;
    const int q   = tid >> 7;          // 4 row-quarters
    int r0 = q << 5;
    if (q > 0 && sDst[r0] == sDst[r0 - 1]){
      int pd = sDst[r0 - 1];
      int rcap = (q << 5) + 32;
      while (r0 < rcap && sDst[r0] == pd) r0++;
    }
    const int rend = (q << 5) + 32;
    for (int r = r0; r < rend; ){
      int d = sDst[r];
      float s = 0.f;
      int rr = r;
      while (rr < 128 && sDst[rr] == d){
        s += Cs[rr * 128 + ((col + ((rr & 7) << 2)) & 127)];
        rr++;
      }
      if (d < n_nodes)
        atomicAdd(agg + (long)d * D + h * NB + col, s);
      r = rr;
    }
  }
}

__global__ __launch_bounds__(256) void finish(
    const float* __restrict__ agg, const int* __restrict__ cnt_i,
    const float* __restrict__ H, const float* __restrict__ bias_f,
    const float* __restrict__ bias_b, const float* __restrict__ gamma,
    const float* __restrict__ beta, float* __restrict__ out, int n_nodes)
{
  const int n = blockIdx.x;
  const int j = threadIdx.x;
  int cf = cnt_i[n], cb = cnt_i[n_nodes + n];
  float c = (float)(cf + cb); c = c < 1.f ? 1.f : c;
  float a = (agg[(long)n * D + j] + (float)cf * bias_f[j] + (float)cb * bias_b[j]) / c;
  float x = (a > 0.f ? a : LEAKY * a) + H[(long)n * D + j];
  float s1 = x, s2 = x * x;
  #pragma unroll
  for (int off = 32; off > 0; off >>= 1){
    s1 += __shfl_xor(s1, off);
    s2 += __shfl_xor(s2, off);
  }
  __shared__ float rs[8];
  if ((j & 63) == 0){ rs[j >> 6] = s1; rs[4 + (j >> 6)] = s2; }
  __syncthreads();
  float t1 = rs[0] + rs[1] + rs[2] + rs[3];
  float t2 = rs[4] + rs[5] + rs[6] + rs[7];
  float mu = t1 * (1.f / D);
  float var = t2 * (1.f / D) - mu * mu;
  float r = rsqrtf(var + EPS);
  out[(long)n * D + j] = (x - mu) * r * gamma[j] + beta[j];
}

extern "C" void kernel_launch(void* const* d_in, const int* in_sizes, int n_in,
                              void* d_out, int out_size, void* d_ws, size_t ws_size,
                              hipStream_t stream)
{
  const float* H      = (const float*)d_in[0];
  const float* E      = (const float*)d_in[1];
  const int*   ht     = (const int*)d_in[2];
  const float* W_fwd  = (const float*)d_in[3];
  const float* b_fwd  = (const float*)d_in[4];
  const float* W_back = (const float*)d_in[5];
  const float* b_back = (const float*)d_in[6];
  const float* gamma  = (const float*)d_in[7];
  const float* beta   = (const float*)d_in[8];
  float* out = (float*)d_out;

  const int n_nodes = in_sizes[0] / D;
  const int n_edges = in_sizes[2] / 2;
  const int N2 = 2 * n_nodes;
  const int NM = 2 * n_edges;

  char* p = (char*)d_ws;
  float* agg    = (float*)p;  p += (size_t)n_nodes * D * 4;
  int*   cnt_i  = (int*)p;    p += (size_t)N2 * 4;
  int*   cursor = (int*)p;    p += (size_t)N2 * 4;
  size_t zbytes = (size_t)(p - (char*)d_ws);          // agg + cnt + cursor
  int*   off    = (int*)p;    p += (size_t)N2 * 4;
  int*   bsum   = (int*)p;    p += 128 * 4;
  int*   bases  = (int*)p;    p += 128 * 4;
  int*   perm   = (int*)p;    p += (size_t)NM * 4;
  int*   dstS   = (int*)p;    p += (size_t)NM * 4;
  int*   hS     = (int*)p;    p += (size_t)NM * 4;
  unsigned short* Wimg = (unsigned short*)p;

  const int nscan = (N2 + 1023) / 1024;

  hipMemsetAsync(d_ws, 0, zbytes, stream);
  prep_w<<<(2 * 2 * NCHUNK * NB * BK) / 256, 256, 0, stream>>>(W_fwd, W_back, Wimg);
  count2<<<(n_edges + 255) / 256, 256, 0, stream>>>(ht, cnt_i, n_edges, n_nodes);
  scan_sums<<<nscan, 1024, 0, stream>>>(cnt_i, bsum, N2);
  scan_bases<<<1, 64, 0, stream>>>(bsum, bases, nscan);
  scan_off<<<nscan, 1024, 0, stream>>>(cnt_i, bases, off, N2);
  scatter_msgs<<<(NM + 255) / 256, 256, 0, stream>>>(ht, off, cursor, perm, dstS, hS,
                                                     n_edges, n_nodes);
  const int ntiles = (n_edges + TE - 1) / TE;
  edge_gemm<<<ntiles * 4, 512, 0, stream>>>(H, E, perm, dstS, hS, Wimg, agg,
                                            n_edges, n_nodes);
  finish<<<n_nodes, 256, 0, stream>>>(agg, cnt_i, H, b_fwd, b_back, gamma, beta,
                                      out, n_nodes);
}

// Round 12
// 471.660 us; speedup vs baseline: 3.5483x; 1.0542x over previous
//
#include <hip/hip_runtime.h>
#include <hip/hip_bf16.h>

#define D 256
#define TE 128         // messages per tile
#define NB 128         // output cols per block (colhalf)
#define BK 64          // K-chunk
#define NCHUNK 12      // 4 groups x [E | E*H | H]
#define LEAKY 0.01f
#define EPS 1e-5f

typedef float f32x4 __attribute__((ext_vector_type(4)));
typedef short s16x8 __attribute__((ext_vector_type(8)));

__device__ __forceinline__ unsigned short f2bf(float f){
  union { float f; unsigned int u; } v; v.f = f;
  unsigned int u = v.u;
  return (unsigned short)((u + 0x7fffu + ((u >> 16) & 1u)) >> 16);
}
// HW pack: D.lo = bf16(lo), D.hi = bf16(hi), RNE — 1 VALU op.
__device__ __forceinline__ unsigned int cvtpk(float lo, float hi){
  unsigned int r;
  asm("v_cvt_pk_bf16_f32 %0, %1, %2" : "=v"(r) : "v"(lo), "v"(hi));
  return r;
}

// Fragment-major bf16 image of folded weights (R10-proven layout):
// tile t = (dir*2+h)*12 + c (16 KB each); within: [ks][j][lane][e]
// col = h*128 + j*16 + (lane&15); k_local = ks*32 + (lane>>4)*8 + e; x = g*64+k_local.
// A wave's B-fragment load is 64 lanes x 16B CONTIGUOUS (1 KB).
__global__ void prep_w(const float* __restrict__ Wf, const float* __restrict__ Wb,
                       unsigned short* __restrict__ Wimg)
{
  int i = blockIdx.x * 256 + threadIdx.x;       // 2*2*12*8192 = 393216
  int inner = i & 8191;
  int t = i >> 13;                              // (dir*2+h)*12 + c
  int c = t % 12;
  int q = t / 12;
  int dir = q >> 1, h = q & 1;
  int g = c / 3, part = c - g * 3;
  int e    = inner & 7;
  int lane = (inner >> 3) & 63;
  int j    = (inner >> 9) & 7;
  int ks   = inner >> 12;
  int kloc = ks * 32 + (lane >> 4) * 8 + e;
  int x = g * 64 + kloc;                        // original feature index
  int col = h * NB + j * 16 + (lane & 15);
  const float* row = (dir ? Wb : Wf) + (long)col * (4 * D);
  // raw = [Hh | E | Hh+E | Hh*E]:
  float v;
  if (part == 0)      v = row[256 + x] + row[512 + x];   // E coeff
  else if (part == 1) v = row[768 + x];                  // Hh*E coeff
  else                v = row[x] + row[512 + x];         // Hh coeff
  Wimg[(size_t)t * 8192 + inner] = f2bf(v);
}

// Per-dir dst histogram: cnt[0..n) = fwd (dst=tail), cnt[n..2n) = back (dst=head)
__global__ void count2(const int* __restrict__ ht, int* __restrict__ cnt,
                       int n_edges, int n_nodes)
{
  int e = blockIdx.x * 256 + threadIdx.x;
  if (e < n_edges){
    atomicAdd(&cnt[ht[2*e+1]], 1);
    atomicAdd(&cnt[n_nodes + ht[2*e]], 1);
  }
}

__global__ void scan_sums(const int* __restrict__ cnt, int* __restrict__ bsum, int N2)
{
  int t = threadIdx.x, b = blockIdx.x;
  int i = b * 1024 + t;
  int v = (i < N2) ? cnt[i] : 0;
  #pragma unroll
  for (int o = 32; o > 0; o >>= 1) v += __shfl_down(v, o);
  __shared__ int red[16];
  int lane = t & 63, wv = t >> 6;
  if (lane == 0) red[wv] = v;
  __syncthreads();
  if (t == 0){ int s = 0; for (int k = 0; k < 16; ++k) s += red[k]; bsum[b] = s; }
}

__global__ void scan_bases(const int* __restrict__ bsum, int* __restrict__ bases, int nb)
{
  if (threadIdx.x == 0 && blockIdx.x == 0){
    int a = 0;
    for (int k = 0; k < nb; ++k){ bases[k] = a; a += bsum[k]; }
  }
}

__global__ void scan_off(const int* __restrict__ cnt, const int* __restrict__ bases,
                         int* __restrict__ off, int N2)
{
  int t = threadIdx.x, b = blockIdx.x;
  int i = b * 1024 + t;
  int v = (i < N2) ? cnt[i] : 0;
  int lane = t & 63, wv = t >> 6;
  int x = v;
  #pragma unroll
  for (int o = 1; o < 64; o <<= 1){ int y = __shfl_up(x, o); if (lane >= o) x += y; }
  __shared__ int ws[16];
  if (lane == 63) ws[wv] = x;
  __syncthreads();
  if (t == 0){ int a = 0; for (int k = 0; k < 16; ++k){ int tmp = ws[k]; ws[k] = a; a += tmp; } }
  __syncthreads();
  if (i < N2) off[i] = bases[b] + ws[wv] + x - v;
}

// Build dst-sorted lists: positions [0,NE) = fwd sorted by tail, [NE,2NE) = back by head.
__global__ void scatter_msgs(const int* __restrict__ ht, const int* __restrict__ off,
                             int* __restrict__ cursor, int* __restrict__ perm,
                             int* __restrict__ dstS, int* __restrict__ hS,
                             int n_edges, int n_nodes)
{
  int m = blockIdx.x * 256 + threadIdx.x;
  if (m >= 2 * n_edges) return;
  int e  = (m < n_edges) ? m : m - n_edges;
  int hd = ht[2*e], tl = ht[2*e+1];
  int dst = (m < n_edges) ? tl : hd;
  int oth = (m < n_edges) ? hd : tl;
  int idx = ((m < n_edges) ? 0 : n_nodes) + dst;
  int pos = off[idx] + atomicAdd(&cursor[idx], 1);
  perm[pos] = e; dstS[pos] = dst; hS[pos] = oth;
}

// R11 structure, but B lives in registers (fragment-major image, coalesced
// 1KB loads, double-buffered) — LDS carries only the A tile (80KB/chunk vs
// 128KB). __syncthreads loop unchanged (proven R7/R11).
__global__ __launch_bounds__(512, 4) void edge_gemm(
    const float* __restrict__ H, const float* __restrict__ E,
    const int* __restrict__ perm, const int* __restrict__ dstS,
    const int* __restrict__ hS, const unsigned short* __restrict__ Wimg,
    float* __restrict__ agg, int n_edges, int n_nodes)
{
  __shared__ char smem[65536];     // loop: A dbuf in first 32K; epilogue: Cs 64K
  __shared__ int sDst[TE];
  char (*sAl)[16384] = (char(*)[16384])smem;

  // Bijective XCD-chunked swizzle: 4 q-blocks of a tile on the same XCD.
  const int nwg  = gridDim.x;
  const int orig = blockIdx.x;
  const int xcd  = orig & 7;
  const int lq = nwg >> 3, lr = nwg & 7;
  const int L = (xcd < lr ? xcd * (lq + 1) : lr * (lq + 1) + (xcd - lr) * lq)
                + (orig >> 3);
  const int tile = L >> 2;
  const int dir  = (L >> 1) & 1;
  const int h    = L & 1;
  const int pos0 = tile * TE;      // within dir-list

  const int tid  = threadIdx.x;
  const int lane = tid & 63;
  const int wave = tid >> 6;      // 0..7

  // A staging: thread -> 4 rows x 4 cols. cg = col group, rows rg*4+i.
  const int cg = tid & 15;
  const int rg = tid >> 4;        // 0..31
  const float* eptr[4]; const float* hptr[4];
  #pragma unroll
  for (int i = 0; i < 4; ++i){
    int row = rg * 4 + i;
    int rp  = pos0 + row;
    bool pad = (rp >= n_edges);
    int gpos = dir * n_edges + (pad ? (n_edges - 1) : rp);
    eptr[i] = E + (long)perm[gpos] * D;
    hptr[i] = H + (long)hS[gpos] * D;
    if (cg == 0) sDst[row] = pad ? 0x7fffffff : dstS[gpos];
  }
  __syncthreads();

  const char* wqB = (const char*)Wimg + (size_t)(dir * 2 + h) * NCHUNK * 16384
                    + lane * 16;

  f32x4 acc[4][2];
  #pragma unroll
  for (int mi = 0; mi < 4; ++mi)
    #pragma unroll
    for (int ni = 0; ni < 2; ++ni)
      acc[mi][ni] = (f32x4){0.f, 0.f, 0.f, 0.f};

  float4 sl0[4], sl1[4];          // A reg slots: A(x) -> slot (x&1)
  float4 Ev[4];                   // persistent E regs across a part-triplet
  s16x8 bA[4], bB[4];             // B frag dbuf: chunk c uses (c&1)?bB:bA

  const int rlo = lane & 15;
  const int khi = lane >> 4;
  const int wm = wave >> 2;       // 0..1: 64-row slab
  const int wn = wave & 3;        // 0..3: 32-col slab

  #define ISSUE_A(c) {                                                       \
    const int g_ = (c) / 3, part_ = (c) % 3;                                 \
    float4* dst_ = ((c) & 1) ? sl1 : sl0;                                    \
    _Pragma("unroll")                                                        \
    for (int i = 0; i < 4; ++i)                                              \
      dst_[i] = *(const float4*)((part_ == 0 ? eptr[i] : hptr[i])            \
                                 + g_ * 64 + cg * 4);                        \
  }

  #define WRITE_A(c, buf) {                                                  \
    const int part_ = (c) % 3;                                               \
    float4* src_ = ((c) & 1) ? sl1 : sl0;                                    \
    _Pragma("unroll")                                                        \
    for (int i = 0; i < 4; ++i){                                             \
      int row = rg * 4 + i;                                                  \
      float4 v;                                                              \
      if (part_ == 0){ Ev[i] = src_[i]; v = src_[i]; }                       \
      else if (part_ == 1) v = make_float4(Ev[i].x*src_[i].x,                \
          Ev[i].y*src_[i].y, Ev[i].z*src_[i].z, Ev[i].w*src_[i].w);          \
      else v = src_[i];                                                      \
      uint2 w; w.x = cvtpk(v.x, v.y); w.y = cvtpk(v.z, v.w);                 \
      int off = (row * 128 + cg * 8) ^ ((row & 7) << 4);                     \
      *(uint2*)(&sAl[buf][off]) = w;                                         \
    }                                                                        \
  }

  // 4 coalesced 16B loads: B frags (ks 0/1) x (ni 0/1) for this wave's cols.
  #define LOAD_B(c, dst_) {                                                  \
    const char* bb = wqB + (size_t)(c) * 16384;                              \
    dst_[0] = *(const s16x8*)(bb + (wn * 2 + 0) * 1024);                     \
    dst_[1] = *(const s16x8*)(bb + (wn * 2 + 1) * 1024);                     \
    dst_[2] = *(const s16x8*)(bb + 8192 + (wn * 2 + 0) * 1024);              \
    dst_[3] = *(const s16x8*)(bb + 8192 + (wn * 2 + 1) * 1024);              \
  }

  // ---- Prologue ----
  ISSUE_A(0);
  ISSUE_A(1);
  LOAD_B(0, bA);
  WRITE_A(0, 0);
  ISSUE_A(2);
  __syncthreads();

  // ---- Main loop ----
  #pragma unroll
  for (int c = 0; c < NCHUNK; ++c){
    const int cur = c & 1;
    if (c + 1 < NCHUNK){
      if (cur) { LOAD_B(c + 1, bA); } else { LOAD_B(c + 1, bB); }
      WRITE_A(c + 1, cur ^ 1);
    }
    if (c + 3 < NCHUNK){
      ISSUE_A(c + 3);
    }
    #pragma unroll
    for (int ks = 0; ks < 2; ++ks){
      const int kb = (ks * 32 + khi * 8) * 2;
      s16x8 af[4];
      #pragma unroll
      for (int mi = 0; mi < 4; ++mi){
        int row = wm * 64 + mi * 16 + rlo;
        af[mi] = *(const s16x8*)(&sAl[cur][(row * 128 + kb) ^ ((row & 7) << 4)]);
      }
      #pragma unroll
      for (int mi = 0; mi < 4; ++mi)
        #pragma unroll
        for (int ni = 0; ni < 2; ++ni)
          acc[mi][ni] = __builtin_amdgcn_mfma_f32_16x16x32_bf16(
              af[mi], cur ? bB[ks * 2 + ni] : bA[ks * 2 + ni],
              acc[mi][ni], 0, 0, 0);
    }
    if (c + 1 < NCHUNK) __syncthreads();
  }
  #undef ISSUE_A
  #undef WRITE_A
  #undef LOAD_B

  // ---- Epilogue: C -> LDS, segmented run-reduce over dst-sorted rows ----
  __syncthreads();                 // all MFMA LDS reads done; smem reusable
  float* Cs = (float*)smem;        // [128][128], bank-rotated by row
  #pragma unroll
  for (int mi = 0; mi < 4; ++mi)
    #pragma unroll
    for (int ni = 0; ni < 2; ++ni)
      #pragma unroll
      for (int r = 0; r < 4; ++r){
        int row = wm * 64 + mi * 16 + khi * 4 + r;
        int col = wn * 32 + ni * 16 + rlo;
        int cw = (col + ((row & 7) << 2)) & 127;
        Cs[row * 128 + cw] = acc[mi][ni][r];
      }
  __syncthreads();

  {
    const int col = tid & 127;
    const int q   = tid >> 7;          // 4 row-quarters
    int r0 = q << 5;
    if (q > 0 && sDst[r0] == sDst[r0 - 1]){
      int pd = sDst[r0 - 1];
      int rcap = (q << 5) + 32;
      while (r0 < rcap && sDst[r0] == pd) r0++;
    }
    const int rend = (q << 5) + 32;
    for (int r = r0; r < rend; ){
      int d = sDst[r];
      float s = 0.f;
      int rr = r;
      while (rr < 128 && sDst[rr] == d){
        s += Cs[rr * 128 + ((col + ((rr & 7) << 2)) & 127)];
        rr++;
      }
      if (d < n_nodes)
        atomicAdd(agg + (long)d * D + h * NB + col, s);
      r = rr;
    }
  }
}

__global__ __launch_bounds__(256) void finish(
    const float* __restrict__ agg, const int* __restrict__ cnt_i,
    const float* __restrict__ H, const float* __restrict__ bias_f,
    const float* __restrict__ bias_b, const float* __restrict__ gamma,
    const float* __restrict__ beta, float* __restrict__ out, int n_nodes)
{
  const int n = blockIdx.x;
  const int j = threadIdx.x;
  int cf = cnt_i[n], cb = cnt_i[n_nodes + n];
  float c = (float)(cf + cb); c = c < 1.f ? 1.f : c;
  float a = (agg[(long)n * D + j] + (float)cf * bias_f[j] + (float)cb * bias_b[j]) / c;
  float x = (a > 0.f ? a : LEAKY * a) + H[(long)n * D + j];
  float s1 = x, s2 = x * x;
  #pragma unroll
  for (int off = 32; off > 0; off >>= 1){
    s1 += __shfl_xor(s1, off);
    s2 += __shfl_xor(s2, off);
  }
  __shared__ float rs[8];
  if ((j & 63) == 0){ rs[j >> 6] = s1; rs[4 + (j >> 6)] = s2; }
  __syncthreads();
  float t1 = rs[0] + rs[1] + rs[2] + rs[3];
  float t2 = rs[4] + rs[5] + rs[6] + rs[7];
  float mu = t1 * (1.f / D);
  float var = t2 * (1.f / D) - mu * mu;
  float r = rsqrtf(var + EPS);
  out[(long)n * D + j] = (x - mu) * r * gamma[j] + beta[j];
}

extern "C" void kernel_launch(void* const* d_in, const int* in_sizes, int n_in,
                              void* d_out, int out_size, void* d_ws, size_t ws_size,
                              hipStream_t stream)
{
  const float* H      = (const float*)d_in[0];
  const float* E      = (const float*)d_in[1];
  const int*   ht     = (const int*)d_in[2];
  const float* W_fwd  = (const float*)d_in[3];
  const float* b_fwd  = (const float*)d_in[4];
  const float* W_back = (const float*)d_in[5];
  const float* b_back = (const float*)d_in[6];
  const float* gamma  = (const float*)d_in[7];
  const float* beta   = (const float*)d_in[8];
  float* out = (float*)d_out;

  const int n_nodes = in_sizes[0] / D;
  const int n_edges = in_sizes[2] / 2;
  const int N2 = 2 * n_nodes;
  const int NM = 2 * n_edges;

  char* p = (char*)d_ws;
  float* agg    = (float*)p;  p += (size_t)n_nodes * D * 4;
  int*   cnt_i  = (int*)p;    p += (size_t)N2 * 4;
  int*   cursor = (int*)p;    p += (size_t)N2 * 4;
  size_t zbytes = (size_t)(p - (char*)d_ws);          // agg + cnt + cursor
  int*   off    = (int*)p;    p += (size_t)N2 * 4;
  int*   bsum   = (int*)p;    p += 128 * 4;
  int*   bases  = (int*)p;    p += 128 * 4;
  int*   perm   = (int*)p;    p += (size_t)NM * 4;
  int*   dstS   = (int*)p;    p += (size_t)NM * 4;
  int*   hS     = (int*)p;    p += (size_t)NM * 4;
  unsigned short* Wimg = (unsigned short*)p;

  const int nscan = (N2 + 1023) / 1024;

  hipMemsetAsync(d_ws, 0, zbytes, stream);
  prep_w<<<(2 * 2 * NCHUNK * 8192) / 256, 256, 0, stream>>>(W_fwd, W_back, Wimg);
  count2<<<(n_edges + 255) / 256, 256, 0, stream>>>(ht, cnt_i, n_edges, n_nodes);
  scan_sums<<<nscan, 1024, 0, stream>>>(cnt_i, bsum, N2);
  scan_bases<<<1, 64, 0, stream>>>(bsum, bases, nscan);
  scan_off<<<nscan, 1024, 0, stream>>>(cnt_i, bases, off, N2);
  scatter_msgs<<<(NM + 255) / 256, 256, 0, stream>>>(ht, off, cursor, perm, dstS, hS,
                                                     n_edges, n_nodes);
  const int ntiles = (n_edges + TE - 1) / TE;
  edge_gemm<<<ntiles * 4, 512, 0, stream>>>(H, E, perm, dstS, hS, Wimg, agg,
                                            n_edges, n_nodes);
  finish<<<n_nodes, 256, 0, stream>>>(agg, cnt_i, H, b_fwd, b_back, gamma, beta,
                                      out, n_nodes);
}